// Round 4
// baseline (28.597 us; speedup 1.0000x reference)
//
#include <hip/hip_runtime.h>
#include <math.h>

#define H 768
#define ISZ 512
#define IN1 513   // I+1
#define NARM 32
#define NU_C 0.1f

// U region offsets (elements)
#define U_WIH 0
#define U_WHH (3072*513)                 // 1575936
#define U_BIH (U_WHH + 3072*768)         // 3935232
#define U_BHH (U_BIH + 3072)             // 3938304
#define U_FCW (U_BHH + 3072)             // 3941376
#define U_FCB (U_FCW + 32*768)           // 3965952

// out offsets (elements)
#define O_SELR 0
#define O_PROB 1
#define O_SELA 33
#define O_HN   34
#define O_CN   (34+768)
#define O_U    (34+768+768)   // 1570

// ws layout (float units)
#define W_D    0        // 4*768 D factors (gate-major)
#define W_HN   3072     // 768 h_new
#define W_HZ   3840     // int: 1 if h0 has any nonzero
#define W_SEL  3841     // int: selected arm
#define W_PART 4096     // 192 blocks x 96 partials (r[32], s[32], q[32])

#define NPREP 192
#define NCOPY 480
#define WHH_F4 589824   // 3072*768/4

__device__ inline float wave_reduce(float v) {
    for (int d = 32; d > 0; d >>= 1) v += __shfl_xor(v, d, 64);
    return v;
}

__device__ inline float frcp(float x) { return __builtin_amdgcn_rcpf(x); }

__device__ inline void store_f4_as_2xf2(float* p, float4 v) {
    *(float2*)p = make_float2(v.x, v.y);
    *(float2*)(p + 2) = make_float2(v.z, v.w);
}

// K1: blocks [0,192): one wave per j (0..767): gates GEMV + rowsums + D +
//     wsum + per-arm (r,s,q) contributions, block-reduced to 96 partials.
//     blocks [192,672): copy U_WHH -> out when h0 == 0 (no sel needed).
__global__ __launch_bounds__(256) void k1_prep(
    const float* __restrict__ x, const float* __restrict__ prevr,
    const float* __restrict__ h0, const float* __restrict__ c0,
    const float* __restrict__ Wih, const float* __restrict__ Whh,
    const float* __restrict__ bih, const float* __restrict__ bhh,
    const float* __restrict__ fcW, const float* __restrict__ fcb,
    const float* __restrict__ U,
    float* __restrict__ out, float* __restrict__ ws)
{
    int wave = threadIdx.x >> 6;
    int lane = threadIdx.x & 63;

    // every block: load h0 (768 floats) as float4, detect nonzero
    float4 hv4[3];
    bool nzb = false;
    #pragma unroll
    for (int it = 0; it < 3; ++it) {
        hv4[it] = *(const float4*)(h0 + lane * 4 + it * 256);
        nzb |= (hv4[it].x != 0.f) || (hv4[it].y != 0.f) ||
               (hv4[it].z != 0.f) || (hv4[it].w != 0.f);
    }
    const bool hnz = (__ballot(nzb) != 0ull);

    if (blockIdx.x >= NPREP) {
        // ---- copy lane for U_WHH (valid only when h0 == 0) ----
        if (blockIdx.x == NPREP && threadIdx.x == 0)
            ((int*)ws)[W_HZ] = hnz ? 1 : 0;
        if (hnz) return;   // K3 will do the full W_hh update
        const float4* src = (const float4*)(U + U_WHH);
        float* dst = out + O_U + U_WHH;   // 8B-aligned (offset even)
        for (int i = (blockIdx.x - NPREP) * 256 + threadIdx.x;
             i < WHH_F4; i += NCOPY * 256) {
            float4 v = src[i];
            store_f4_as_2xf2(dst + (size_t)i * 4, v);
        }
        return;
    }

    // ---- prep wave: j in [0,768) ----
    int j = blockIdx.x * 4 + wave;
    const float pr = prevr[0];
    const float* r0 = Wih + (size_t)(0*H + j) * IN1;
    const float* r1 = Wih + (size_t)(1*H + j) * IN1;
    const float* r2 = Wih + (size_t)(2*H + j) * IN1;
    const float* r3 = Wih + (size_t)(3*H + j) * IN1;
    const float* u0 = U + U_WIH + (size_t)(0*H + j) * IN1;
    const float* u1 = U + U_WIH + (size_t)(1*H + j) * IN1;
    const float* u2 = U + U_WIH + (size_t)(2*H + j) * IN1;
    const float* u3 = U + U_WIH + (size_t)(3*H + j) * IN1;
    float a0 = 0.f, a1 = 0.f, a2 = 0.f, a3 = 0.f;   // gate GEMV
    float t0 = 0.f, t1 = 0.f, t2 = 0.f, t3 = 0.f;   // rowsum T
    for (int k = lane; k < IN1; k += 64) {
        float xv = (k < ISZ) ? x[k] : pr;
        float x2 = xv * xv;
        a0 += r0[k] * xv;  t0 += x2 * frcp(u0[k]);
        a1 += r1[k] * xv;  t1 += x2 * frcp(u1[k]);
        a2 += r2[k] * xv;  t2 += x2 * frcp(u2[k]);
        a3 += r3[k] * xv;  t3 += x2 * frcp(u3[k]);
    }
    if (hnz) {
        const float* s0 = Whh + (size_t)(0*H + j) * H;
        const float* s1 = Whh + (size_t)(1*H + j) * H;
        const float* s2 = Whh + (size_t)(2*H + j) * H;
        const float* s3 = Whh + (size_t)(3*H + j) * H;
        const float* v0 = U + U_WHH + (size_t)(0*H + j) * H;
        const float* v1 = U + U_WHH + (size_t)(1*H + j) * H;
        const float* v2 = U + U_WHH + (size_t)(2*H + j) * H;
        const float* v3 = U + U_WHH + (size_t)(3*H + j) * H;
        #pragma unroll
        for (int it = 0; it < 3; ++it) {
            int c = lane * 4 + it * 256;
            float4 h4 = hv4[it];
            float4 w, u;
            w = *(const float4*)(s0 + c); u = *(const float4*)(v0 + c);
            a0 += w.x*h4.x + w.y*h4.y + w.z*h4.z + w.w*h4.w;
            t0 += h4.x*h4.x*frcp(u.x) + h4.y*h4.y*frcp(u.y)
                + h4.z*h4.z*frcp(u.z) + h4.w*h4.w*frcp(u.w);
            w = *(const float4*)(s1 + c); u = *(const float4*)(v1 + c);
            a1 += w.x*h4.x + w.y*h4.y + w.z*h4.z + w.w*h4.w;
            t1 += h4.x*h4.x*frcp(u.x) + h4.y*h4.y*frcp(u.y)
                + h4.z*h4.z*frcp(u.z) + h4.w*h4.w*frcp(u.w);
            w = *(const float4*)(s2 + c); u = *(const float4*)(v2 + c);
            a2 += w.x*h4.x + w.y*h4.y + w.z*h4.z + w.w*h4.w;
            t2 += h4.x*h4.x*frcp(u.x) + h4.y*h4.y*frcp(u.y)
                + h4.z*h4.z*frcp(u.z) + h4.w*h4.w*frcp(u.w);
            w = *(const float4*)(s3 + c); u = *(const float4*)(v3 + c);
            a3 += w.x*h4.x + w.y*h4.y + w.z*h4.z + w.w*h4.w;
            t3 += h4.x*h4.x*frcp(u.x) + h4.y*h4.y*frcp(u.y)
                + h4.z*h4.z*frcp(u.z) + h4.w*h4.w*frcp(u.w);
        }
    }
    a0 = wave_reduce(a0); a1 = wave_reduce(a1);
    a2 = wave_reduce(a2); a3 = wave_reduce(a3);
    t0 = wave_reduce(t0); t1 = wave_reduce(t1);
    t2 = wave_reduce(t2); t3 = wave_reduce(t3);

    // all lanes compute the scalar tail identically (loads broadcast)
    float zi = a0 + bih[0*H + j] + bhh[0*H + j];
    float zf = a1 + bih[1*H + j] + bhh[1*H + j];
    float zg = a2 + bih[2*H + j] + bhh[2*H + j];
    float zo = a3 + bih[3*H + j] + bhh[3*H + j];
    float ig = 1.f / (1.f + expf(-zi));
    float fg = 1.f / (1.f + expf(-zf));
    float gg = tanhf(zg);
    float og = 1.f / (1.f + expf(-zo));
    float cj = c0[j];
    float cn = fg * cj + ig * gg;
    float th = tanhf(cn);
    float hn = og * th;
    float dtc = og * (1.f - th * th);
    float D0 = dtc * gg * ig * (1.f - ig);
    float D1 = dtc * cj * fg * (1.f - fg);
    float D2 = dtc * ig * (1.f - gg * gg);
    float D3 = th * og * (1.f - og);
    float T0 = t0 + frcp(U[U_BIH + 0*H + j]) + frcp(U[U_BHH + 0*H + j]);
    float T1 = t1 + frcp(U[U_BIH + 1*H + j]) + frcp(U[U_BHH + 1*H + j]);
    float T2 = t2 + frcp(U[U_BIH + 2*H + j]) + frcp(U[U_BHH + 2*H + j]);
    float T3 = t3 + frcp(U[U_BIH + 3*H + j]) + frcp(U[U_BHH + 3*H + j]);
    float wsum = D0*D0*T0 + D1*D1*T1 + D2*D2*T2 + D3*D3*T3;

    if (lane == 0) {
        ws[W_D + 0*H + j] = D0;
        ws[W_D + 1*H + j] = D1;
        ws[W_D + 2*H + j] = D2;
        ws[W_D + 3*H + j] = D3;
        ws[W_HN + j] = hn;
        out[O_HN + j] = hn;
        out[O_CN + j] = cn;
    }

    // per-arm contributions of this j, block-reduced to 96 floats
    __shared__ float part[4][96];
    if (lane < 32) {
        float fw = fcW[(size_t)lane * H + j];
        float uf = U[U_FCW + (size_t)lane * H + j];
        float rc = fw * hn;
        float sc = fw * fw * wsum;
        float qc = hn * hn * frcp(uf);
        if (blockIdx.x == 0 && wave == 0) {
            rc += fcb[lane];
            qc += frcp(U[U_FCB + lane]);
        }
        part[wave][lane]      = rc;
        part[wave][32 + lane] = sc;
        part[wave][64 + lane] = qc;
    }
    __syncthreads();
    int t = threadIdx.x;
    if (t < 96)
        ws[W_PART + (size_t)blockIdx.x * 96 + t] =
            part[0][t] + part[1][t] + part[2][t] + part[3][t];
}

// K2: 1 block x 128: reduce 192x96 partials, UCB select, softmax, outputs.
__global__ __launch_bounds__(128) void k2_select(
    float* __restrict__ out, float* __restrict__ ws)
{
    __shared__ float red[96];
    int t = threadIdx.x;
    if (t < 96) {
        float s = 0.f;
        #pragma unroll 8
        for (int b = 0; b < NPREP; ++b)
            s += ws[W_PART + (size_t)b * 96 + t];
        red[t] = s;
    }
    __syncthreads();
    if (t < NARM) {
        float r = red[t];
        float s = red[32 + t];
        float q = red[64 + t];
        // inclusive prefix sum of q across 32 lanes
        float cum = q;
        for (int d = 1; d < 32; d <<= 1) {
            float v = __shfl_up(cum, d, 32);
            if (t >= d) cum += v;
        }
        float sc = r + NU_C * sqrtf(s + cum);
        // argmax (first max wins ties)
        float best = sc; int sel = t;
        for (int d = 16; d > 0; d >>= 1) {
            float ob = __shfl_xor(best, d, 32);
            int   oi = __shfl_xor(sel, d, 32);
            if (ob > best || (ob == best && oi < sel)) { best = ob; sel = oi; }
        }
        // softmax over r
        float mx = r;
        for (int d = 16; d > 0; d >>= 1) mx = fmaxf(mx, __shfl_xor(mx, d, 32));
        float e = expf(r - mx);
        float se = e;
        for (int d = 16; d > 0; d >>= 1) se += __shfl_xor(se, d, 32);
        out[O_PROB + t] = e / se;
        float rsel = __shfl(r, sel, 32);
        if (t == 0) {
            out[O_SELR] = rsel;
            out[O_SELA] = (float)sel;
            ((int*)ws)[W_SEL] = sel;
        }
    }
}

// K3: sel-dependent U_new regions. W_hh only when h0 != 0.
// grid: [0,3072) W_ih rows | [3072,5376) W_hh f4 | 6 bias | 24 fcW | 1 fcb
#define B_A 3072
#define B_B (B_A + 2304)
#define B_C (B_B + 6)
#define B_D (B_C + 24)
__global__ __launch_bounds__(256) void k3_unew(
    const float* __restrict__ x, const float* __restrict__ prevr,
    const float* __restrict__ h0, const float* __restrict__ fcW,
    const float* __restrict__ U, float* __restrict__ out,
    const float* __restrict__ ws)
{
    const int sel = ((const int*)ws)[W_SEL];
    int b = blockIdx.x, t = threadIdx.x;
    float* Un = out + O_U;
    if (b < B_A) {                 // W_ih rows, one row per block (513 elems)
        int g = b / H, j = b - g * H;
        float s = fcW[(size_t)sel * H + j] * ws[W_D + g*H + j];
        float s2 = s * s;
        const float* u = U + U_WIH + (size_t)b * IN1;
        float* o = Un + U_WIH + (size_t)b * IN1;
        float xv1 = x[t];
        float xv2 = x[t + 256];
        o[t]       = u[t]       + s2 * xv1 * xv1;
        o[t + 256] = u[t + 256] + s2 * xv2 * xv2;
        if (t == 0) {
            float pr = prevr[0];
            o[512] = u[512] + s2 * pr * pr;
        }
    } else if (b < B_B) {          // W_hh flat float4 (skip if copied by K1)
        const int hz = ((const int*)ws)[W_HZ];
        if (!hz) return;
        int e = ((b - B_A) * 256 + t) * 4;   // < 2359296
        float4 u4 = *(const float4*)(U + U_WHH + e);
        int r = e / H;
        int g = r / H, j = r - g * H;
        int k = e - r * H;
        float s = fcW[(size_t)sel * H + j] * ws[W_D + g*H + j];
        float s2 = s * s;
        float4 h4 = *(const float4*)(h0 + k);
        float4 o4;
        o4.x = u4.x + s2 * h4.x * h4.x;
        o4.y = u4.y + s2 * h4.y * h4.y;
        o4.z = u4.z + s2 * h4.z * h4.z;
        o4.w = u4.w + s2 * h4.w * h4.w;
        store_f4_as_2xf2(Un + U_WHH + e, o4);
    } else if (b < B_C) {          // biases: 6144 elems, float4
        int m = ((b - B_B) * 256 + t) * 4;
        int r = (m < 3072) ? m : m - 3072;
        int g = r / H, j = r - g * H;
        float4 f4 = *(const float4*)(fcW + (size_t)sel * H + j);
        float4 d4 = *(const float4*)(ws + W_D + g*H + j);
        float4 u4 = *(const float4*)(U + U_BIH + m);
        float4 o4;
        float sx = f4.x*d4.x, sy = f4.y*d4.y, sz = f4.z*d4.z, sw = f4.w*d4.w;
        o4.x = u4.x + sx*sx; o4.y = u4.y + sy*sy;
        o4.z = u4.z + sz*sz; o4.w = u4.w + sw*sw;
        store_f4_as_2xf2(Un + U_BIH + m, o4);
    } else if (b < B_D) {          // fc_W: 24576 elems, float4
        int e = ((b - B_C) * 256 + t) * 4;
        int a = e / H, j = e - a * H;
        float4 h4 = *(const float4*)(ws + W_HN + j);
        float4 u4 = *(const float4*)(U + U_FCW + e);
        float m = (a <= sel) ? 1.f : 0.f;
        float4 o4;
        o4.x = u4.x + m * h4.x * h4.x;
        o4.y = u4.y + m * h4.y * h4.y;
        o4.z = u4.z + m * h4.z * h4.z;
        o4.w = u4.w + m * h4.w * h4.w;
        store_f4_as_2xf2(Un + U_FCW + e, o4);
    } else {                       // fc_b
        if (t < NARM)
            Un[U_FCB + t] = U[U_FCB + t] + ((t <= sel) ? 1.f : 0.f);
    }
}

extern "C" void kernel_launch(void* const* d_in, const int* in_sizes, int n_in,
                              void* d_out, int out_size, void* d_ws, size_t ws_size,
                              hipStream_t stream) {
    const float* x     = (const float*)d_in[0];
    const float* prevr = (const float*)d_in[1];
    const float* h0    = (const float*)d_in[2];
    const float* c0    = (const float*)d_in[3];
    const float* Wih   = (const float*)d_in[4];
    const float* Whh   = (const float*)d_in[5];
    const float* bih   = (const float*)d_in[6];
    const float* bhh   = (const float*)d_in[7];
    const float* fcW   = (const float*)d_in[8];
    const float* fcb   = (const float*)d_in[9];
    const float* U     = (const float*)d_in[10];
    float* out = (float*)d_out;
    float* ws  = (float*)d_ws;

    hipLaunchKernelGGL(k1_prep, dim3(NPREP + NCOPY), dim3(256), 0, stream,
                       x, prevr, h0, c0, Wih, Whh, bih, bhh, fcW, fcb, U, out, ws);
    hipLaunchKernelGGL(k2_select, dim3(1), dim3(128), 0, stream,
                       out, ws);
    hipLaunchKernelGGL(k3_unew, dim3(B_D + 1), dim3(256), 0, stream,
                       x, prevr, h0, fcW, U, out, ws);
}